// Round 7
// baseline (169.229 us; speedup 1.0000x reference)
//
#include <hip/hip_runtime.h>

#define TEMP    0.5f
#define LOG2E   1.4426950408889634f
#define C2      (LOG2E / TEMP)        /* t = dot * C2 */
#define MSHIFT  160.0f                /* fixed base-2 softmax shift */
#define LN2     0.6931471805599453f
#define NROWS   16384
#define BHALF   8192
#define DDIM    128
#define PREPB   2048                  /* k_prep blocks = 524288/256 */
#define MAINB   512                   /* k_main grid: 64 rb x 8 cc */

typedef __bf16 bf16x8 __attribute__((ext_vector_type(8)));
typedef float  f32x16 __attribute__((ext_vector_type(16)));

__device__ __forceinline__ float fexp2(float x) {
#if __has_builtin(__builtin_amdgcn_exp2f)
  return __builtin_amdgcn_exp2f(x);
#else
  return exp2f(x);
#endif
}

__device__ __forceinline__ unsigned short f2bf(float f) {
  unsigned int u = __float_as_uint(f);
  unsigned int r = (u + 0x7FFFu + ((u >> 16) & 1u)) >> 16;  // RNE
  return (unsigned short)r;
}

// ---------------------------------------------------------------------------
// zbF frag-major layout: row r, k-index k:
//   g = r/32, lo = r%32, khi = k/8, j = k%8
//   short index = g*4096 + khi*256 + lo*8 + j
// A wave's frag load (fixed khi): 64 lanes read a contiguous 1KB block.
// ---------------------------------------------------------------------------

__global__ void k_prep(const float* __restrict__ zi, const float* __restrict__ zj,
                       unsigned short* __restrict__ zbF,
                       float* __restrict__ S, float* __restrict__ Pp,
                       unsigned int* __restrict__ Cnt) {
  const int t   = blockIdx.x * 256 + threadIdx.x;   // 0..524287 float4 groups
  const int row = t >> 5;                           // 32 float4 per 128-elt row
  const int k0  = (t & 31) * 4;
  const float* src = (row < BHALF) ? (zi + (size_t)row * DDIM)
                                   : (zj + (size_t)(row - BHALF) * DDIM);
  float4 v = *reinterpret_cast<const float4*>(src + k0);

  const int g = row >> 5, lo = row & 31, khi = k0 >> 3, j0 = k0 & 7;
  ushort4 o;
  o.x = f2bf(v.x); o.y = f2bf(v.y); o.z = f2bf(v.z); o.w = f2bf(v.w);
  *reinterpret_cast<ushort4*>(zbF + (size_t)g * 4096 + khi * 256 + lo * 8 + j0) = o;

  float dot = 0.f;
  if (row < BHALF) {
    float4 w = *reinterpret_cast<const float4*>(zj + (size_t)row * DDIM + k0);
    dot = fmaf(v.x, w.x, fmaf(v.y, w.y, fmaf(v.z, w.z, v.w * w.w)));
  }
#pragma unroll
  for (int m = 32; m >= 1; m >>= 1) dot += __shfl_xor(dot, m, 64);
  __shared__ float red[4];
  if ((threadIdx.x & 63) == 0) red[threadIdx.x >> 6] = dot;
  __syncthreads();
  if (threadIdx.x == 0) Pp[blockIdx.x] = red[0] + red[1] + red[2] + red[3];

  if (t < NROWS) S[t] = 0.f;
  if (t == 0)    *Cnt = 0u;
}

// ---------------------------------------------------------------------------
// k_main: 64 persistent rows/wave (B operand, 2 row-tiles), streams 32-col
// tiles as A. PAIRED chains (two independent MFMA dep-chains vs b0/b1 fill
// the MFMA result-latency gap) + cross-iteration ping-pong (exp of tile t-1
// issues under tile t's chains). ~192 live regs -> 2 waves/SIMD, spill-free.
// ---------------------------------------------------------------------------
__device__ __forceinline__ void loadA(bf16x8 (&a)[8], const unsigned short* ap) {
#pragma unroll
  for (int ks = 0; ks < 8; ++ks)
    a[ks] = *reinterpret_cast<const bf16x8*>(ap + ks * 512);
}

__device__ __forceinline__ void chainPair(const bf16x8 (&a)[8],
                                          const bf16x8 (&b0)[8], const bf16x8 (&b1)[8],
                                          const f32x16& z, f32x16& o0, f32x16& o1) {
  o0 = __builtin_amdgcn_mfma_f32_32x32x16_bf16(a[0], b0[0], z, 0, 0, 0);
  o1 = __builtin_amdgcn_mfma_f32_32x32x16_bf16(a[0], b1[0], z, 0, 0, 0);
#pragma unroll
  for (int ks = 1; ks < 8; ++ks) {
    o0 = __builtin_amdgcn_mfma_f32_32x32x16_bf16(a[ks], b0[ks], o0, 0, 0, 0);
    o1 = __builtin_amdgcn_mfma_f32_32x32x16_bf16(a[ks], b1[ks], o1, 0, 0, 0);
  }
}

template <bool MK>
__device__ __forceinline__ void expPair(const f32x16& A0, const f32x16& A1,
                                        float& s0, float& s1, int d0, int d1, int hi) {
  float u0 = 0.f, u1 = 0.f, w0 = 0.f, w1 = 0.f;
#pragma unroll
  for (int r = 0; r < 16; ++r) {
    float e0 = fexp2(fmaf(A0[r], C2, -MSHIFT));
    float e1 = fexp2(fmaf(A1[r], C2, -MSHIFT));
    if (MK) {
      const int rloc = (r & 3) + 8 * (r >> 2) + 4 * hi;  // C/D reg map (verified)
      if (rloc == d0) e0 = 0.f;
      if (rloc == d1) e1 = 0.f;
    }
    if (r & 1) { u1 += e0; w1 += e1; }
    else       { u0 += e0; w0 += e1; }
  }
  s0 += u0 + u1;
  s1 += w0 + w1;
}

__device__ __forceinline__ void expDispatch(const f32x16& A0, const f32x16& A1,
                                            float& s0, float& s1,
                                            int dr, int lo, int hi) {
  if (dr == 0 || dr == 32)
    expPair<true >(A0, A1, s0, s1, dr == 0 ? lo : -1, dr == 32 ? lo : -1, hi);
  else
    expPair<false>(A0, A1, s0, s1, -1, -1, hi);
}

__global__ __launch_bounds__(256, 2)
void k_main(const unsigned short* __restrict__ zbF, float* __restrict__ S,
            const float* __restrict__ Pp, unsigned int* __restrict__ Cnt,
            float* __restrict__ out) {
  const int wave = threadIdx.x >> 6;
  const int lane = threadIdx.x & 63;
  const int lo = lane & 31;
  const int hi = lane >> 5;
  const int rb = blockIdx.x & 63;       // 64 row blocks of 256 rows
  const int cc = blockIdx.x >> 6;       // 8 col chunks of 2048 cols
  const int row0w = rb * 256 + wave * 64;

  // persistent row frags (B operand): 2 row-tiles x 8 k-steps = 64 regs
  bf16x8 b0[8], b1[8];
  loadA(b0, zbF + (size_t)(row0w >> 5)       * 4096 + hi * 256 + lo * 8);
  loadA(b1, zbF + (size_t)((row0w >> 5) + 1) * 4096 + hi * 256 + lo * 8);

  float s0 = 0.f, s1 = 0.f;
  const f32x16 kZ = {};

  const int c0base = cc * 2048;
  const unsigned short* abase = zbF + (size_t)(c0base >> 5) * 4096 + hi * 256 + lo * 8;

  bf16x8 a[8];
  loadA(a, abase);                       // tile 0

  f32x16 E0, E1, O0, O1;
  chainPair(a, b0, b1, kZ, E0, E1);      // tile 0
  loadA(a, abase + 4096);                // tile 1

  for (int k = 0; k < 32; ++k) {
    const int t1 = 2 * k + 1;

    chainPair(a, b0, b1, kZ, O0, O1);                        // tile t1
    if (t1 + 1 < 64) loadA(a, abase + (size_t)(t1 + 1) * 4096);
    expDispatch(E0, E1, s0, s1, c0base + (t1 - 1) * 32 - row0w, lo, hi);

    if (t1 + 1 < 64) {
      chainPair(a, b0, b1, kZ, E0, E1);                      // tile t1+1
      if (t1 + 2 < 64) loadA(a, abase + (size_t)(t1 + 2) * 4096);
    }
    expDispatch(O0, O1, s0, s1, c0base + t1 * 32 - row0w, lo, hi);
  }

  // row sums: fold hi halves, one atomic per row per col-chunk
  s0 += __shfl_xor(s0, 32, 64);
  s1 += __shfl_xor(s1, 32, 64);
  if (hi == 0) {
    atomicAdd(&S[row0w + lo],      s0);
    atomicAdd(&S[row0w + 32 + lo], s1);
  }

  // ---- fused finalize: last block computes the loss ----
  __threadfence();
  __shared__ bool isLast;
  if (threadIdx.x == 0)
    isLast = (atomicAdd(Cnt, 1u) == MAINB - 1);
  __syncthreads();
  if (!isLast) return;
  __threadfence();

  const int t = threadIdx.x;
  float q = 0.f;
  for (int r = t; r < NROWS; r += 256) {
    float sv = __hip_atomic_load(&S[r], __ATOMIC_RELAXED, __HIP_MEMORY_SCOPE_AGENT);
    q += LN2 * (MSHIFT + __log2f(sv));
  }
  for (int r = t; r < PREPB; r += 256)
    q -= 4.0f * Pp[r];
  __shared__ float red[256];
  red[t] = q;
  __syncthreads();
  for (int s2 = 128; s2 > 0; s2 >>= 1) {
    if (t < s2) red[t] += red[t + s2];
    __syncthreads();
  }
  if (t == 0) out[0] = red[0] / (float)NROWS;
}

// ---------------------------------------------------------------------------
extern "C" void kernel_launch(void* const* d_in, const int* in_sizes, int n_in,
                              void* d_out, int out_size, void* d_ws, size_t ws_size,
                              hipStream_t stream) {
  const float* zi = (const float*)d_in[0];
  const float* zj = (const float*)d_in[1];
  unsigned short* zbF = (unsigned short*)d_ws;                     // 4 MB
  float* S  = (float*)((char*)d_ws + (size_t)NROWS * DDIM * 2);    // 64 KB
  float* Pp = S + NROWS;                                           // 8 KB
  unsigned int* Cnt = (unsigned int*)(Pp + PREPB);                 // 4 B
  float* out = (float*)d_out;

  hipLaunchKernelGGL(k_prep, dim3(PREPB), dim3(256), 0, stream, zi, zj, zbF, S, Pp, Cnt);
  hipLaunchKernelGGL(k_main, dim3(MAINB), dim3(256), 0, stream, zbF, S, Pp, Cnt, out);
}